// Round 2
// baseline (29586.093 us; speedup 1.0000x reference)
//
#include <hip/hip_runtime.h>

#define C_ 128
#define KS_ 9
#define B_ 8
#define H_ 128
#define W_ 256
#define HW_ (H_ * W_)    // 32768
#define CHW_ (C_ * HW_)  // 4194304

typedef _Float16 half8 __attribute__((ext_vector_type(8)));
typedef float floatx4 __attribute__((ext_vector_type(4)));

// ---------------- init: copy x -> Y (d_out used as working fp32 image) ----------------
__global__ void k_copy(const float* __restrict__ in, float* __restrict__ out, int n4) {
  int i = blockIdx.x * blockDim.x + threadIdx.x;
  int stride = gridDim.x * blockDim.x;
  const floatx4* ip = (const floatx4*)in;
  floatx4* op = (floatx4*)out;
  for (; i < n4; i += stride) op[i] = ip[i];
}

// ---------------- weight prep: fp32 [co][ci][kk] -> f16 fragment order ----------------
// Element [mt(8)][ks(36)][lane(64)][j(8)] = f16( W[co = mt*16 + (lane&15)][ci = k&127][kk = k>>7] ),
// k = ks*32 + (lane>>4)*8 + j   (A-operand: m = lane&15, k-frag = quad*8 + j)
__global__ void k_wprep(const float* w0, const float* w1, const float* w2, const float* w3,
                        _Float16* __restrict__ wf) {
  const float* Wp[4] = {w0, w1, w2, w3};
  const float* W = Wp[blockIdx.y];
  _Float16* out = wf + (size_t)blockIdx.y * (8 * 36 * 64 * 8);
  int idx = blockIdx.x * 256 + threadIdx.x;
  if (idx >= 8 * 36 * 64 * 8) return;
  int j = idx & 7;
  int lane = (idx >> 3) & 63;
  int ks = (idx >> 9) % 36;
  int mt = (idx >> 9) / 36;
  int co = mt * 16 + (lane & 15);
  int k = ks * 32 + ((lane >> 4) & 3) * 8 + j;
  int kk = k >> 7, ci = k & 127;
  out[idx] = (_Float16)W[((size_t)co * C_ + ci) * KS_ + kk];
}

// ---------------- shared GEMM core: acc[mt] += W * carry, K = 1152 ----------------
// Bl: [local col (80)][ci (128)] f16.  wrow_base = wave*16 + (lane&15) + 4 (kk added inside).
__device__ __forceinline__ void gemm_acc(const _Float16* Bl,
                                         const _Float16* __restrict__ Wfrag,
                                         int wrow_base, int lane, floatx4* acc) {
  const int q = lane >> 4;
  const half8* wfp = (const half8*)Wfrag + lane;
  for (int ks = 0; ks < 36; ++ks) {
    int k0 = ks * 32 + q * 8;
    int kk = k0 >> 7;      // k = kk*128 + ci
    int ci0 = k0 & 127;
    half8 bf = *(const half8*)&Bl[(size_t)(wrow_base + kk) * C_ + ci0];
    const half8* wp = wfp + ks * 64;
#pragma unroll
    for (int mt = 0; mt < 8; ++mt)
      acc[mt] = __builtin_amdgcn_mfma_f32_16x16x32_f16(wp[mt * 36 * 64], bf, acc[mt], 0, 0, 0);
  }
}

// ---------------- vertical step: scan over H, conv/cols along W (contiguous) ----------------
// Y[b][c][row][:] += relu(conv1d(Y[b][:][prev][:]))
__global__ __launch_bounds__(256) void k_step_v(float* __restrict__ Y,
                                                const _Float16* __restrict__ Wfrag,
                                                int row, int prev) {
  __shared__ _Float16 Bl[80 * 128];
  const int b = blockIdx.y;
  const int w0 = blockIdx.x * 64;
  const int t = threadIdx.x;

  // stage carry row fp32 -> f16 LDS, cols [w0-8, w0+72)
  {
    const float* base = Y + (size_t)b * CHW_ + (size_t)prev * W_;
#pragma unroll
    for (int it = 0; it < 10; ++it) {
      int c = it * 256 + t;  // 2560 chunks of 4 cols
      int ci = c / 20, c4 = c % 20;
      int wst = w0 - 8 + c4 * 4;
      const float* p = base + (size_t)ci * HW_ + wst;
      float v[4];
      if (wst >= 0 && wst + 4 <= W_) {
        floatx4 u = *(const floatx4*)p;
        v[0] = u[0]; v[1] = u[1]; v[2] = u[2]; v[3] = u[3];
      } else {
#pragma unroll
        for (int j = 0; j < 4; ++j) {
          int w = wst + j;
          v[j] = (w >= 0 && w < W_) ? p[j] : 0.f;
        }
      }
      int wl = c4 * 4;
#pragma unroll
      for (int j = 0; j < 4; ++j) Bl[(wl + j) * C_ + ci] = (_Float16)v[j];
    }
  }
  __syncthreads();

  const int lane = t & 63;
  const int wave = t >> 6;
  const int q = lane >> 4;
  const int l15 = lane & 15;

  floatx4 acc[8];
#pragma unroll
  for (int mt = 0; mt < 8; ++mt) acc[mt] = (floatx4){0.f, 0.f, 0.f, 0.f};

  gemm_acc(Bl, Wfrag, wave * 16 + l15 + 4, lane, acc);

  const int wcol = w0 + wave * 16 + l15;  // D: n = lane&15
#pragma unroll
  for (int mt = 0; mt < 8; ++mt) {
#pragma unroll
    for (int r = 0; r < 4; ++r) {
      int co = mt * 16 + q * 4 + r;  // D: m = (lane>>4)*4 + r
      size_t off = (size_t)b * CHW_ + (size_t)co * HW_ + (size_t)row * W_ + wcol;
      Y[off] = Y[off] + fmaxf(acc[mt][r], 0.f);
    }
  }
}

// ---------------- horizontal step: scan over W (stride 1), conv/cols along H (stride W_) ----------------
// Y[b][c][:][row] += relu(conv1d_overH(Y[b][:][:][prev]))
__global__ __launch_bounds__(256) void k_step_h(float* __restrict__ Y,
                                                const _Float16* __restrict__ Wfrag,
                                                int row, int prev) {
  __shared__ _Float16 Bl[80 * 128];
  const int b = blockIdx.y;
  const int h0 = blockIdx.x * 64;
  const int t = threadIdx.x;

  // stage carry column fp32 -> f16 LDS, h in [h0-8, h0+72)  (strided scalar loads)
  {
    const float* base = Y + (size_t)b * CHW_ + prev;
    for (int e = t; e < 80 * 128; e += 256) {
      int hl = e >> 7;       // local col [0,80)
      int ci = e & 127;
      int h = h0 - 8 + hl;
      float v = 0.f;
      if (h >= 0 && h < H_) v = base[(size_t)ci * HW_ + (size_t)h * W_];
      Bl[hl * C_ + ci] = (_Float16)v;
    }
  }
  __syncthreads();

  const int lane = t & 63;
  const int wave = t >> 6;
  const int q = lane >> 4;
  const int l15 = lane & 15;

  floatx4 acc[8];
#pragma unroll
  for (int mt = 0; mt < 8; ++mt) acc[mt] = (floatx4){0.f, 0.f, 0.f, 0.f};

  gemm_acc(Bl, Wfrag, wave * 16 + l15 + 4, lane, acc);

  const int hc = h0 + wave * 16 + l15;  // D: n = lane&15  (this is an H index)
#pragma unroll
  for (int mt = 0; mt < 8; ++mt) {
#pragma unroll
    for (int r = 0; r < 4; ++r) {
      int co = mt * 16 + q * 4 + r;
      size_t off = (size_t)b * CHW_ + (size_t)co * HW_ + (size_t)hc * W_ + row;
      Y[off] = Y[off] + fmaxf(acc[mt][r], 0.f);
    }
  }
}

extern "C" void kernel_launch(void* const* d_in, const int* in_sizes, int n_in,
                              void* d_out, int out_size, void* d_ws, size_t ws_size,
                              hipStream_t stream) {
  const float* x = (const float*)d_in[0];
  const float* w_ud = (const float*)d_in[1];
  const float* w_du = (const float*)d_in[2];
  const float* w_lr = (const float*)d_in[3];
  const float* w_rl = (const float*)d_in[4];

  float* Y = (float*)d_out;            // working fp32 image [B][C][H][W]
  _Float16* Wf = (_Float16*)d_ws;      // ONLY ws use: 4 * 294,912 B fragment weights

  const size_t WF_PASS = 8 * 36 * 64 * 8;

  k_copy<<<2048, 256, 0, stream>>>(x, Y, B_ * C_ * H_ * W_ / 4);
  k_wprep<<<dim3(576, 4), 256, 0, stream>>>(w_ud, w_du, w_lr, w_rl, Wf);

  // pass 1: up -> down (scan H forward), conv along W
  for (int i = 1; i < H_; ++i)
    k_step_v<<<dim3(W_ / 64, B_), 256, 0, stream>>>(Y, Wf + 0 * WF_PASS, i, i - 1);

  // pass 2: down -> up (scan H backward)
  for (int i = H_ - 2; i >= 0; --i)
    k_step_v<<<dim3(W_ / 64, B_), 256, 0, stream>>>(Y, Wf + 1 * WF_PASS, i, i + 1);

  // pass 3: left -> right (scan W forward), conv along H — strided, no transpose
  for (int i = 1; i < W_; ++i)
    k_step_h<<<dim3(H_ / 64, B_), 256, 0, stream>>>(Y, Wf + 2 * WF_PASS, i, i - 1);

  // pass 4: right -> left (scan W backward)
  for (int i = W_ - 2; i >= 0; --i)
    k_step_h<<<dim3(H_ / 64, B_), 256, 0, stream>>>(Y, Wf + 3 * WF_PASS, i, i + 1);
}

// Round 3
// 16972.980 us; speedup vs baseline: 1.7431x; 1.7431x over previous
//
#include <hip/hip_runtime.h>

#define C_ 128
#define KS_ 9
#define B_ 8
#define H_ 128
#define W_ 256
#define HW_ (H_ * W_)    // 32768
#define CHW_ (C_ * HW_)  // 4194304

typedef _Float16 half8 __attribute__((ext_vector_type(8)));
typedef float floatx4 __attribute__((ext_vector_type(4)));
typedef unsigned long long ull;

// ws layout (primary path)
#define WS_WF_OFF    0u
#define WS_WF_BYTES  1179648u            // 4 passes * 294,912 B fragment weights
#define WS_FLAGS_OFF 1179648u            // 4096 B of flags (1024 ints)
#define WS_CARRY_OFF 1183744u            // 2 parity * 8 b * 256 col * 128 ci * 2B = 1,048,576
#define WS_YT_OFF    2232320u            // f16 transposed image: 8*128*256*128*2 = 16,777,216
#define WS_NEED      19009536u

// ---------------- utility kernels ----------------
__global__ void k_copy(const float* __restrict__ in, float* __restrict__ out, int n4) {
  int i = blockIdx.x * blockDim.x + threadIdx.x;
  int stride = gridDim.x * blockDim.x;
  const floatx4* ip = (const floatx4*)in;
  floatx4* op = (floatx4*)out;
  for (; i < n4; i += stride) op[i] = ip[i];
}

__global__ void k_zero(int* p) { p[blockIdx.x * 256 + threadIdx.x] = 0; }

// weight prep: fp32 [co][ci][kk] -> f16 A-fragment order
// idx = (((mt8)*36 + ks)*64 + lane)*8 + j ; co = mt8*16 + (lane&15); k = ks*32 + q*8 + j
__global__ void k_wprep(const float* w0, const float* w1, const float* w2, const float* w3,
                        _Float16* __restrict__ wf) {
  const float* Wp[4] = {w0, w1, w2, w3};
  const float* W = Wp[blockIdx.y];
  _Float16* out = wf + (size_t)blockIdx.y * (8 * 36 * 64 * 8);
  int idx = blockIdx.x * 256 + threadIdx.x;
  if (idx >= 8 * 36 * 64 * 8) return;
  int j = idx & 7;
  int lane = (idx >> 3) & 63;
  int ks = (idx >> 9) % 36;
  int mt = (idx >> 9) / 36;
  int co = mt * 16 + (lane & 15);
  int k = ks * 32 + ((lane >> 4) & 3) * 8 + j;
  int kk = k >> 7, ci = k & 127;
  out[idx] = (_Float16)W[((size_t)co * C_ + ci) * KS_ + kk];
}

// transpose fp32 NCHW -> f16 [b][c][w][h]
__global__ void k_t1(const float* __restrict__ in, _Float16* __restrict__ out) {
  __shared__ float tile[32][33];
  size_t pbase = (size_t)blockIdx.z * HW_;
  int h0 = blockIdx.y * 32, w0 = blockIdx.x * 32;
  int tx = threadIdx.x, ty = threadIdx.y;
  for (int i = 0; i < 32; i += 8)
    tile[ty + i][tx] = in[pbase + (size_t)(h0 + ty + i) * W_ + (w0 + tx)];
  __syncthreads();
  for (int i = 0; i < 32; i += 8)
    out[pbase + (size_t)(w0 + ty + i) * H_ + (h0 + tx)] = (_Float16)tile[tx][ty + i];
}

// transpose f16 [b][c][w][h] -> fp32 NCHW
__global__ void k_t2(const _Float16* __restrict__ in, float* __restrict__ out) {
  __shared__ float tile[32][33];
  size_t pbase = (size_t)blockIdx.z * HW_;
  int h0 = blockIdx.y * 32, w0 = blockIdx.x * 32;
  int tx = threadIdx.x, ty = threadIdx.y;
  for (int i = 0; i < 32; i += 8)
    tile[ty + i][tx] = (float)in[pbase + (size_t)(w0 + ty + i) * H_ + (h0 + tx)];
  __syncthreads();
  for (int i = 0; i < 32; i += 8)
    out[pbase + (size_t)(h0 + ty + i) * W_ + (w0 + tx)] = tile[tx][ty + i];
}

// ---------------- persistent scan kernel (one launch per pass) ----------------
// img: [B][128][S][L] of YT. carry: [2][8][256][128] f16. fl: [b][T] step counters.
// WG (tile, cb, b): cols [tile*64, +64), couts [cb*32, +32). 4 waves x 16 cols.
template <typename YT>
__global__ __launch_bounds__(256, 1) void k_scan(YT* __restrict__ img,
                                                 const _Float16* __restrict__ Wf,
                                                 _Float16* __restrict__ carry,
                                                 int* __restrict__ fl,
                                                 int S, int L, int T, int dir, int istart) {
  __shared__ _Float16 Bl[80 * 132];  // carry patch [lcol 80][ci 128], row stride 132 halves
  const int tile = blockIdx.x % T;
  const int cb = blockIdx.x / T;
  const int b = blockIdx.y;
  const int t = threadIdx.x;
  const int lane = t & 63;
  const int wave = t >> 6;
  const int q = lane >> 4;
  const int m = lane & 15;
  const int cbase = cb * 32;
  const int col0 = tile * 64;

  // ---- A-fragments -> registers (once per pass): 2 m-tiles x 36 ks x half8 ----
  half8 A0[36], A1[36];
  {
    const half8* wp = (const half8*)Wf;
#pragma unroll
    for (int ks = 0; ks < 36; ++ks) {
      A0[ks] = wp[(((cb * 2 + 0) * 36 + ks) * 64) + lane];
      A1[ks] = wp[(((cb * 2 + 1) * 36 + ks) * 64) + lane];
    }
  }

  // ---- init: publish row `istart` (this WG's cols x ci-block) as carry parity 0 ----
  {
    int col = col0 + (t >> 2);
    int ci0 = cbase + (t & 3) * 8;
    float v[8];
#pragma unroll
    for (int u = 0; u < 8; ++u)
      v[u] = (float)img[((size_t)(b * C_ + ci0 + u) * S + istart) * L + col];
    union { ull u[2]; _Float16 h[8]; } pk;
#pragma unroll
    for (int u = 0; u < 8; ++u) pk.h[u] = (_Float16)v[u];
    ull* dst = (ull*)(carry + ((size_t)b * 256 + col) * 128 + ci0);
    __hip_atomic_store(&dst[0], pk.u[0], __ATOMIC_RELAXED, __HIP_MEMORY_SCOPE_AGENT);
    __hip_atomic_store(&dst[1], pk.u[1], __ATOMIC_RELAXED, __HIP_MEMORY_SCOPE_AGENT);
    __threadfence();
    __syncthreads();
    if (t == 0)
      __hip_atomic_fetch_add(&fl[b * T + tile], 1, __ATOMIC_RELEASE, __HIP_MEMORY_SCOPE_AGENT);
  }

  // ---- scan loop ----
  for (int n = 1; n < S; ++n) {
    const int row = istart + dir * n;
    const int pp = (n - 1) & 1;
    const int pc = n & 1;

    // x-term prefetch (independent of carry; issue before spin to hide latency)
    const int mycol = col0 + wave * 16 + m;
    float xv[2][4];
#pragma unroll
    for (int mt = 0; mt < 2; ++mt)
#pragma unroll
      for (int r = 0; r < 4; ++r) {
        int co = cbase + mt * 16 + q * 4 + r;
        xv[mt][r] = (float)__builtin_nontemporal_load(
            img + ((size_t)(b * C_ + co) * S + row) * L + mycol);
      }

    // spin for neighbor tiles (incl own) at step n-1
    if (wave == 0 && lane < 3) {
      int tt = tile - 1 + lane;
      if (tt >= 0 && tt < T) {
        const int tgt = 4 * n;
        while (__hip_atomic_load(&fl[b * T + tt], __ATOMIC_RELAXED, __HIP_MEMORY_SCOPE_AGENT) < tgt)
          __builtin_amdgcn_s_sleep(1);
      }
    }
    __syncthreads();
    __threadfence();  // acquire: invalidate stale cache for carry reads

    // stage carry parity pp -> LDS (cols [col0-8, col0+72), zero-padded)
    {
      const _Float16* cr = carry + ((size_t)(pp * 8 + b)) * (256 * 128);
#pragma unroll
      for (int it = 0; it < 5; ++it) {
        int e = it * 256 + t;       // 1280 chunks of 8 halves
        int lcol = e >> 4;
        int cig = (e & 15) * 8;
        int col = col0 - 8 + lcol;
        ull u0 = 0, u1 = 0;
        if (col >= 0 && col < L) {
          const ull* p = (const ull*)(cr + (size_t)col * 128 + cig);
          u0 = p[0];
          u1 = p[1];
        }
        ull* dst = (ull*)(Bl + lcol * 132 + cig);
        dst[0] = u0;
        dst[1] = u1;
      }
    }
    __syncthreads();

    // GEMM: acc[mt] = W(32co x 1152) * carry(1152 x 16col)
    floatx4 acc0 = {0.f, 0.f, 0.f, 0.f}, acc1 = {0.f, 0.f, 0.f, 0.f};
#pragma unroll
    for (int ks = 0; ks < 36; ++ks) {
      const int kk = ks >> 2;
      const int ci0 = (ks & 3) * 32 + q * 8;
      const int lcol = wave * 16 + m + 4 + kk;
      const ull* bp = (const ull*)(Bl + lcol * 132 + ci0);
      union { ull u[2]; half8 v; } bf;
      bf.u[0] = bp[0];
      bf.u[1] = bp[1];
      acc0 = __builtin_amdgcn_mfma_f32_16x16x32_f16(A0[ks], bf.v, acc0, 0, 0, 0);
      acc1 = __builtin_amdgcn_mfma_f32_16x16x32_f16(A1[ks], bf.v, acc1, 0, 0, 0);
    }

    // epilogue: y = x + relu(conv); write img (nontemporal) + carry parity pc (agent stores)
#pragma unroll
    for (int mt = 0; mt < 2; ++mt) {
      union { ull u; _Float16 h[4]; } pk;
      const floatx4 a = mt ? acc1 : acc0;
#pragma unroll
      for (int r = 0; r < 4; ++r) {
        int co = cbase + mt * 16 + q * 4 + r;
        float y = xv[mt][r] + fmaxf(a[r], 0.f);
        __builtin_nontemporal_store((YT)y, img + ((size_t)(b * C_ + co) * S + row) * L + mycol);
        pk.h[r] = (_Float16)y;
      }
      ull* dst = (ull*)(carry + ((size_t)(pc * 8 + b) * 256 + mycol) * 128 + cbase + mt * 16 + q * 4);
      __hip_atomic_store(dst, pk.u, __ATOMIC_RELAXED, __HIP_MEMORY_SCOPE_AGENT);
    }
    __threadfence();  // release side: drain stores before flag bump
    __syncthreads();
    if (t == 0)
      __hip_atomic_fetch_add(&fl[b * T + tile], 1, __ATOMIC_RELEASE, __HIP_MEMORY_SCOPE_AGENT);
  }
}

// ---------------- fallback path (round-2, proven): per-step kernels ----------------
__device__ __forceinline__ void gemm_acc_fb(const _Float16* Bl, const _Float16* __restrict__ Wfrag,
                                            int wrow_base, int lane, floatx4* acc) {
  const int q = lane >> 4;
  const half8* wfp = (const half8*)Wfrag + lane;
  for (int ks = 0; ks < 36; ++ks) {
    int k0 = ks * 32 + q * 8;
    int kk = k0 >> 7;
    int ci0 = k0 & 127;
    half8 bf = *(const half8*)&Bl[(size_t)(wrow_base + kk) * C_ + ci0];
    const half8* wp = wfp + ks * 64;
#pragma unroll
    for (int mt = 0; mt < 8; ++mt)
      acc[mt] = __builtin_amdgcn_mfma_f32_16x16x32_f16(wp[mt * 36 * 64], bf, acc[mt], 0, 0, 0);
  }
}

__global__ __launch_bounds__(256) void k_step_v(float* __restrict__ Y,
                                                const _Float16* __restrict__ Wfrag,
                                                int row, int prev) {
  __shared__ _Float16 Bl[80 * 128];
  const int b = blockIdx.y, w0 = blockIdx.x * 64, t = threadIdx.x;
  {
    const float* base = Y + (size_t)b * CHW_ + (size_t)prev * W_;
#pragma unroll
    for (int it = 0; it < 10; ++it) {
      int c = it * 256 + t;
      int ci = c / 20, c4 = c % 20;
      int wst = w0 - 8 + c4 * 4;
      const float* p = base + (size_t)ci * HW_ + wst;
      float v[4];
      if (wst >= 0 && wst + 4 <= W_) {
        floatx4 u = *(const floatx4*)p;
        v[0] = u[0]; v[1] = u[1]; v[2] = u[2]; v[3] = u[3];
      } else {
#pragma unroll
        for (int j = 0; j < 4; ++j) { int w = wst + j; v[j] = (w >= 0 && w < W_) ? p[j] : 0.f; }
      }
      int wl = c4 * 4;
#pragma unroll
      for (int j = 0; j < 4; ++j) Bl[(wl + j) * C_ + ci] = (_Float16)v[j];
    }
  }
  __syncthreads();
  const int lane = t & 63, wave = t >> 6, q = lane >> 4, l15 = lane & 15;
  floatx4 acc[8];
#pragma unroll
  for (int mt = 0; mt < 8; ++mt) acc[mt] = (floatx4){0.f, 0.f, 0.f, 0.f};
  gemm_acc_fb(Bl, Wfrag, wave * 16 + l15 + 4, lane, acc);
  const int wcol = w0 + wave * 16 + l15;
#pragma unroll
  for (int mt = 0; mt < 8; ++mt)
#pragma unroll
    for (int r = 0; r < 4; ++r) {
      int co = mt * 16 + q * 4 + r;
      size_t off = (size_t)b * CHW_ + (size_t)co * HW_ + (size_t)row * W_ + wcol;
      Y[off] = Y[off] + fmaxf(acc[mt][r], 0.f);
    }
}

__global__ __launch_bounds__(256) void k_step_h(float* __restrict__ Y,
                                                const _Float16* __restrict__ Wfrag,
                                                int row, int prev) {
  __shared__ _Float16 Bl[80 * 128];
  const int b = blockIdx.y, h0 = blockIdx.x * 64, t = threadIdx.x;
  {
    const float* base = Y + (size_t)b * CHW_ + prev;
    for (int e = t; e < 80 * 128; e += 256) {
      int hl = e >> 7, ci = e & 127, h = h0 - 8 + hl;
      float v = 0.f;
      if (h >= 0 && h < H_) v = base[(size_t)ci * HW_ + (size_t)h * W_];
      Bl[hl * C_ + ci] = (_Float16)v;
    }
  }
  __syncthreads();
  const int lane = t & 63, wave = t >> 6, q = lane >> 4, l15 = lane & 15;
  floatx4 acc[8];
#pragma unroll
  for (int mt = 0; mt < 8; ++mt) acc[mt] = (floatx4){0.f, 0.f, 0.f, 0.f};
  gemm_acc_fb(Bl, Wfrag, wave * 16 + l15 + 4, lane, acc);
  const int hc = h0 + wave * 16 + l15;
#pragma unroll
  for (int mt = 0; mt < 8; ++mt)
#pragma unroll
    for (int r = 0; r < 4; ++r) {
      int co = mt * 16 + q * 4 + r;
      size_t off = (size_t)b * CHW_ + (size_t)co * HW_ + (size_t)hc * W_ + row;
      Y[off] = Y[off] + fmaxf(acc[mt][r], 0.f);
    }
}

extern "C" void kernel_launch(void* const* d_in, const int* in_sizes, int n_in,
                              void* d_out, int out_size, void* d_ws, size_t ws_size,
                              hipStream_t stream) {
  const float* x = (const float*)d_in[0];
  const float* w_ud = (const float*)d_in[1];
  const float* w_du = (const float*)d_in[2];
  const float* w_lr = (const float*)d_in[3];
  const float* w_rl = (const float*)d_in[4];

  float* Y = (float*)d_out;  // working fp32 image [B][C][H][W]
  char* ws = (char*)d_ws;
  _Float16* Wf = (_Float16*)(ws + WS_WF_OFF);
  int* flags = (int*)(ws + WS_FLAGS_OFF);
  _Float16* carry = (_Float16*)(ws + WS_CARRY_OFF);
  _Float16* Yt = (_Float16*)(ws + WS_YT_OFF);

  const size_t WF_PASS = 8 * 36 * 64 * 8;

  k_copy<<<2048, 256, 0, stream>>>(x, Y, B_ * C_ * H_ * W_ / 4);
  k_wprep<<<dim3(576, 4), 256, 0, stream>>>(w_ud, w_du, w_lr, w_rl, Wf);

  if (ws_size >= WS_NEED) {
    // ---- primary: persistent neighbor-sync scan kernels ----
    k_zero<<<4, 256, 0, stream>>>(flags);
    // pass 1: scan H forward (T=4 tiles of W)
    k_scan<float><<<dim3(16, 8), 256, 0, stream>>>(Y, Wf + 0 * WF_PASS, carry, flags + 0,
                                                   H_, W_, 4, +1, 0);
    // pass 2: scan H backward
    k_scan<float><<<dim3(16, 8), 256, 0, stream>>>(Y, Wf + 1 * WF_PASS, carry, flags + 32,
                                                   H_, W_, 4, -1, H_ - 1);
    // transpose to f16 [b][c][w][h]
    k_t1<<<dim3(8, 4, B_ * C_), dim3(32, 8), 0, stream>>>(Y, Yt);
    // pass 3: scan W forward (T=2 tiles of H)
    k_scan<_Float16><<<dim3(8, 8), 256, 0, stream>>>(Yt, Wf + 2 * WF_PASS, carry, flags + 64,
                                                     W_, H_, 2, +1, 0);
    // pass 4: scan W backward
    k_scan<_Float16><<<dim3(8, 8), 256, 0, stream>>>(Yt, Wf + 3 * WF_PASS, carry, flags + 96,
                                                     W_, H_, 2, -1, W_ - 1);
    // transpose back to fp32 NCHW in d_out
    k_t2<<<dim3(8, 4, B_ * C_), dim3(32, 8), 0, stream>>>(Yt, Y);
  } else {
    // ---- fallback: proven round-2 per-step path ----
    for (int i = 1; i < H_; ++i)
      k_step_v<<<dim3(W_ / 64, B_), 256, 0, stream>>>(Y, Wf + 0 * WF_PASS, i, i - 1);
    for (int i = H_ - 2; i >= 0; --i)
      k_step_v<<<dim3(W_ / 64, B_), 256, 0, stream>>>(Y, Wf + 1 * WF_PASS, i, i + 1);
    for (int i = 1; i < W_; ++i)
      k_step_h<<<dim3(H_ / 64, B_), 256, 0, stream>>>(Y, Wf + 2 * WF_PASS, i, i - 1);
    for (int i = W_ - 2; i >= 0; --i)
      k_step_h<<<dim3(H_ / 64, B_), 256, 0, stream>>>(Y, Wf + 3 * WF_PASS, i, i + 1);
  }
}